// Round 1
// baseline (1045.198 us; speedup 1.0000x reference)
//
#include <hip/hip_runtime.h>
#include <hip/hip_bf16.h>
#include <stdint.h>

#define NNODES 100000
#define NEDGES 640000
#define CIN 128
#define EDIM 64
#define C2 256

// ---------------------------------------------------------------------------
// K1: per-edge message + scatter-add.
// Work item = (edge, half). One wave covers 64 channels (ch = half*64+lane).
// We column held in 64 VGPRs (loaded once per wave, reused over ~156 edges).
// Edge row address is wave-uniform -> scalar loads. Scatter via HW fp32 atomic.
// ---------------------------------------------------------------------------
__global__ __launch_bounds__(256) void k1_edge(
    const float* __restrict__ x,
    const int* __restrict__ edge_index,
    const float* __restrict__ eattr,
    const float* __restrict__ We,
    const float* __restrict__ be,
    float* __restrict__ h)
{
    const int lane = threadIdx.x & 63;
    const int wib  = __builtin_amdgcn_readfirstlane(threadIdx.x >> 6);
    const int gwid = blockIdx.x * 4 + wib;          // global wave id (uniform)
    const int nw   = gridDim.x * 4;                  // total waves (even)

    const int half = gwid & 1;                       // fixed per wave
    const int ch   = (half << 6) + lane;

    float w[EDIM];
#pragma unroll
    for (int k = 0; k < EDIM; ++k) w[k] = We[k * CIN + ch];
    const float bch = be[ch];

    const int e0      = gwid >> 1;
    const int estride = nw >> 1;
    for (int e = e0; e < NEDGES; e += estride) {
        const int dst = edge_index[e];               // scalar load (uniform)
        const int src = edge_index[NEDGES + e];
        const float xv = x[(size_t)src * CIN + ch];  // coalesced 256B, L3-hot
        float a = bch;
        const float4* __restrict__ er4 = (const float4*)(eattr + (size_t)e * EDIM);
#pragma unroll
        for (int k4 = 0; k4 < EDIM / 4; ++k4) {
            const float4 ev = er4[k4];               // uniform -> s_load_dwordx4
            a = fmaf(ev.x, w[4 * k4 + 0], a);
            a = fmaf(ev.y, w[4 * k4 + 1], a);
            a = fmaf(ev.z, w[4 * k4 + 2], a);
            a = fmaf(ev.w, w[4 * k4 + 3], a);
        }
        const float m = fmaxf(a + xv, 0.0f);
        unsafeAtomicAdd(&h[(size_t)dst * CIN + ch], m);  // global_atomic_add_f32
    }
}

// ---------------------------------------------------------------------------
// K2: h = (1+eps)*x + msum; h1 = relu(LN(h @ W1 + b1)) stored as bf16.
// Thread t = output channel t (256 ch). W1 column in 128 VGPRs.
// 32 nodes/block staged in LDS, processed in batches of 4.
// ---------------------------------------------------------------------------
__global__ __launch_bounds__(256) void k2_mlp1(
    const float* __restrict__ x,
    const float* __restrict__ msum,
    const float* __restrict__ eps,
    const float* __restrict__ W1,
    const float* __restrict__ b1,
    const float* __restrict__ gamma,
    const float* __restrict__ beta,
    __hip_bfloat16* __restrict__ h1)
{
    __shared__ float hs[32][CIN];      // 16 KB
    __shared__ float red[4][4][2];     // [wave][node-in-batch][sum,sumsq]
    const int t    = threadIdx.x;
    const int lane = t & 63;
    const int wv   = t >> 6;
    const int n0   = blockIdx.x * 32;
    const float s1p = 1.0f + eps[0];

    {   // stage h rows = (1+eps)*x + msum
        const float4* __restrict__ xg = (const float4*)(x    + (size_t)n0 * CIN);
        const float4* __restrict__ mg = (const float4*)(msum + (size_t)n0 * CIN);
        float4* __restrict__ hl = (float4*)&hs[0][0];
#pragma unroll
        for (int i = 0; i < 4; ++i) {
            const float4 xv = xg[t + i * 256];
            const float4 mv = mg[t + i * 256];
            float4 r;
            r.x = fmaf(s1p, xv.x, mv.x);
            r.y = fmaf(s1p, xv.y, mv.y);
            r.z = fmaf(s1p, xv.z, mv.z);
            r.w = fmaf(s1p, xv.w, mv.w);
            hl[t + i * 256] = r;
        }
    }

    float w1r[CIN];
#pragma unroll
    for (int k = 0; k < CIN; ++k) w1r[k] = W1[(size_t)k * C2 + t];
    const float b1r = b1[t], gr = gamma[t], br = beta[t];

    __syncthreads();

    for (int nb = 0; nb < 32; nb += 4) {
        float a0 = 0.f, a1 = 0.f, a2 = 0.f, a3 = 0.f;
        const float4* __restrict__ r0 = (const float4*)&hs[nb + 0][0];
        const float4* __restrict__ r1 = (const float4*)&hs[nb + 1][0];
        const float4* __restrict__ r2 = (const float4*)&hs[nb + 2][0];
        const float4* __restrict__ r3 = (const float4*)&hs[nb + 3][0];
#pragma unroll
        for (int k4 = 0; k4 < CIN / 4; ++k4) {
            const float4 v0 = r0[k4];                 // ds_read_b128 broadcast
            a0 = fmaf(v0.x, w1r[4*k4+0], a0);
            a0 = fmaf(v0.y, w1r[4*k4+1], a0);
            a0 = fmaf(v0.z, w1r[4*k4+2], a0);
            a0 = fmaf(v0.w, w1r[4*k4+3], a0);
            const float4 v1 = r1[k4];
            a1 = fmaf(v1.x, w1r[4*k4+0], a1);
            a1 = fmaf(v1.y, w1r[4*k4+1], a1);
            a1 = fmaf(v1.z, w1r[4*k4+2], a1);
            a1 = fmaf(v1.w, w1r[4*k4+3], a1);
            const float4 v2 = r2[k4];
            a2 = fmaf(v2.x, w1r[4*k4+0], a2);
            a2 = fmaf(v2.y, w1r[4*k4+1], a2);
            a2 = fmaf(v2.z, w1r[4*k4+2], a2);
            a2 = fmaf(v2.w, w1r[4*k4+3], a2);
            const float4 v3 = r3[k4];
            a3 = fmaf(v3.x, w1r[4*k4+0], a3);
            a3 = fmaf(v3.y, w1r[4*k4+1], a3);
            a3 = fmaf(v3.z, w1r[4*k4+2], a3);
            a3 = fmaf(v3.w, w1r[4*k4+3], a3);
        }
        a0 += b1r; a1 += b1r; a2 += b1r; a3 += b1r;

        float s0=a0, s1=a1, s2=a2, s3=a3;
        float q0=a0*a0, q1=a1*a1, q2=a2*a2, q3=a3*a3;
#pragma unroll
        for (int off = 32; off > 0; off >>= 1) {
            s0 += __shfl_xor(s0, off); q0 += __shfl_xor(q0, off);
            s1 += __shfl_xor(s1, off); q1 += __shfl_xor(q1, off);
            s2 += __shfl_xor(s2, off); q2 += __shfl_xor(q2, off);
            s3 += __shfl_xor(s3, off); q3 += __shfl_xor(q3, off);
        }
        if (lane == 0) {
            red[wv][0][0]=s0; red[wv][0][1]=q0;
            red[wv][1][0]=s1; red[wv][1][1]=q1;
            red[wv][2][0]=s2; red[wv][2][1]=q2;
            red[wv][3][0]=s3; red[wv][3][1]=q3;
        }
        __syncthreads();
        const float inv = 1.0f / 256.0f;
        {
            const float mu = (red[0][0][0]+red[1][0][0]+red[2][0][0]+red[3][0][0]) * inv;
            const float vv = (red[0][0][1]+red[1][0][1]+red[2][0][1]+red[3][0][1]) * inv - mu*mu;
            const float o  = fmaxf(fmaf((a0 - mu) * rsqrtf(vv + 1e-5f), gr, br), 0.f);
            h1[(size_t)(n0 + nb + 0) * C2 + t] = __float2bfloat16(o);
        }
        {
            const float mu = (red[0][1][0]+red[1][1][0]+red[2][1][0]+red[3][1][0]) * inv;
            const float vv = (red[0][1][1]+red[1][1][1]+red[2][1][1]+red[3][1][1]) * inv - mu*mu;
            const float o  = fmaxf(fmaf((a1 - mu) * rsqrtf(vv + 1e-5f), gr, br), 0.f);
            h1[(size_t)(n0 + nb + 1) * C2 + t] = __float2bfloat16(o);
        }
        {
            const float mu = (red[0][2][0]+red[1][2][0]+red[2][2][0]+red[3][2][0]) * inv;
            const float vv = (red[0][2][1]+red[1][2][1]+red[2][2][1]+red[3][2][1]) * inv - mu*mu;
            const float o  = fmaxf(fmaf((a2 - mu) * rsqrtf(vv + 1e-5f), gr, br), 0.f);
            h1[(size_t)(n0 + nb + 2) * C2 + t] = __float2bfloat16(o);
        }
        {
            const float mu = (red[0][3][0]+red[1][3][0]+red[2][3][0]+red[3][3][0]) * inv;
            const float vv = (red[0][3][1]+red[1][3][1]+red[2][3][1]+red[3][3][1]) * inv - mu*mu;
            const float o  = fmaxf(fmaf((a3 - mu) * rsqrtf(vv + 1e-5f), gr, br), 0.f);
            h1[(size_t)(n0 + nb + 3) * C2 + t] = __float2bfloat16(o);
        }
        __syncthreads();   // protect red[] before next batch
    }
}

// ---------------------------------------------------------------------------
// K3: out = h1 @ W2 + b2.  Thread t -> (j = t&127 out channel, half = t>>7 k-half).
// W2 half-column in 128 VGPRs. 32 nodes/block staged (bf16->f32) in LDS.
// ---------------------------------------------------------------------------
__global__ __launch_bounds__(256) void k3_mlp2(
    const __hip_bfloat16* __restrict__ h1,
    const float* __restrict__ W2,
    const float* __restrict__ b2,
    float* __restrict__ out)
{
    __shared__ float hsf[32 * C2];     // 32 KB
    __shared__ float pbuf[4][CIN];     // 2 KB
    const int t    = threadIdx.x;
    const int j    = t & 127;
    const int half = t >> 7;
    const int n0   = blockIdx.x * 32;

    float w2r[CIN];
#pragma unroll
    for (int k = 0; k < CIN; ++k)
        w2r[k] = W2[(size_t)(half * CIN + k) * CIN + j];
    const float b2r = b2[j];

    {   // stage 32 rows of h1 (bf16) as f32
        const uint32_t* __restrict__ hg = (const uint32_t*)(h1 + (size_t)n0 * C2);
#pragma unroll
        for (int i = 0; i < 16; ++i) {
            const uint32_t u = hg[t + i * 256];
            const int idx = 2 * (t + i * 256);
            hsf[idx]     = __uint_as_float(u << 16);
            hsf[idx + 1] = __uint_as_float(u & 0xffff0000u);
        }
    }
    __syncthreads();

    for (int nb = 0; nb < 32; nb += 4) {
        float p0 = 0.f, p1 = 0.f, p2 = 0.f, p3 = 0.f;
        const float4* __restrict__ r0 = (const float4*)&hsf[(nb+0)*C2 + half*CIN];
        const float4* __restrict__ r1 = (const float4*)&hsf[(nb+1)*C2 + half*CIN];
        const float4* __restrict__ r2 = (const float4*)&hsf[(nb+2)*C2 + half*CIN];
        const float4* __restrict__ r3 = (const float4*)&hsf[(nb+3)*C2 + half*CIN];
#pragma unroll
        for (int k4 = 0; k4 < CIN / 4; ++k4) {
            const float4 v0 = r0[k4];
            p0 = fmaf(v0.x, w2r[4*k4+0], p0);
            p0 = fmaf(v0.y, w2r[4*k4+1], p0);
            p0 = fmaf(v0.z, w2r[4*k4+2], p0);
            p0 = fmaf(v0.w, w2r[4*k4+3], p0);
            const float4 v1 = r1[k4];
            p1 = fmaf(v1.x, w2r[4*k4+0], p1);
            p1 = fmaf(v1.y, w2r[4*k4+1], p1);
            p1 = fmaf(v1.z, w2r[4*k4+2], p1);
            p1 = fmaf(v1.w, w2r[4*k4+3], p1);
            const float4 v2 = r2[k4];
            p2 = fmaf(v2.x, w2r[4*k4+0], p2);
            p2 = fmaf(v2.y, w2r[4*k4+1], p2);
            p2 = fmaf(v2.z, w2r[4*k4+2], p2);
            p2 = fmaf(v2.w, w2r[4*k4+3], p2);
            const float4 v3 = r3[k4];
            p3 = fmaf(v3.x, w2r[4*k4+0], p3);
            p3 = fmaf(v3.y, w2r[4*k4+1], p3);
            p3 = fmaf(v3.z, w2r[4*k4+2], p3);
            p3 = fmaf(v3.w, w2r[4*k4+3], p3);
        }
        if (half) {
            pbuf[0][j] = p0; pbuf[1][j] = p1; pbuf[2][j] = p2; pbuf[3][j] = p3;
        }
        __syncthreads();
        if (!half) {
            out[(size_t)(n0+nb+0)*CIN + j] = p0 + pbuf[0][j] + b2r;
            out[(size_t)(n0+nb+1)*CIN + j] = p1 + pbuf[1][j] + b2r;
            out[(size_t)(n0+nb+2)*CIN + j] = p2 + pbuf[2][j] + b2r;
            out[(size_t)(n0+nb+3)*CIN + j] = p3 + pbuf[3][j] + b2r;
        }
        __syncthreads();
    }
}

// ---------------------------------------------------------------------------
extern "C" void kernel_launch(void* const* d_in, const int* in_sizes, int n_in,
                              void* d_out, int out_size, void* d_ws, size_t ws_size,
                              hipStream_t stream)
{
    const float* x     = (const float*)d_in[0];
    const int*   ei    = (const int*)d_in[1];
    const float* ea    = (const float*)d_in[2];
    const float* We    = (const float*)d_in[3];
    const float* be    = (const float*)d_in[4];
    const float* W1    = (const float*)d_in[5];
    const float* b1    = (const float*)d_in[6];
    const float* gamma = (const float*)d_in[7];
    const float* beta  = (const float*)d_in[8];
    const float* W2    = (const float*)d_in[9];
    const float* b2    = (const float*)d_in[10];
    const float* eps   = (const float*)d_in[11];

    float* h = (float*)d_ws;                                         // 51.2 MB
    __hip_bfloat16* h1 = (__hip_bfloat16*)((char*)d_ws + (size_t)NNODES * CIN * 4); // 51.2 MB

    hipMemsetAsync(h, 0, (size_t)NNODES * CIN * sizeof(float), stream);
    k1_edge<<<1024, 256, 0, stream>>>(x, ei, ea, We, be, h);
    k2_mlp1<<<NNODES / 32, 256, 0, stream>>>(x, h, eps, W1, b1, gamma, beta, h1);
    k3_mlp2<<<NNODES / 32, 256, 0, stream>>>(h1, W2, b2, (float*)d_out);
}

// Round 2
// 897.538 us; speedup vs baseline: 1.1645x; 1.1645x over previous
//
#include <hip/hip_runtime.h>
#include <hip/hip_bf16.h>
#include <stdint.h>

#define NNODES 100000
#define NEDGES 640000
#define CIN 128
#define EDIM 64
#define C2 256

// ---------------------------------------------------------------------------
// CSR build: histogram -> 2-level exclusive scan -> fill permutation.
// counts/cursor live in a 400KB L2-resident array; int atomics only.
// ---------------------------------------------------------------------------
__global__ __launch_bounds__(256) void k_hist(const int* __restrict__ ei,
                                              int* __restrict__ counts)
{
    const int e = blockIdx.x * 256 + threadIdx.x;   // grid sized exactly
    atomicAdd(&counts[ei[e]], 1);                   // dst = edge_index[0][e]
}

#define CHUNK 98   // 1024 chunks * 98 >= 100000

__global__ __launch_bounds__(256) void k_scanA(const int* __restrict__ counts,
                                               int* __restrict__ chunks)
{
    const int c = blockIdx.x * 256 + threadIdx.x;   // 0..1023
    const int n0 = c * CHUNK;
    const int n1 = min(n0 + CHUNK, NNODES);
    int s = 0;
    for (int n = n0; n < n1; ++n) s += counts[n];
    chunks[c] = s;
}

__global__ __launch_bounds__(1024) void k_scanB(int* __restrict__ chunks)
{
    __shared__ int ws[16];
    const int t = threadIdx.x, lane = t & 63, wv = t >> 6;
    const int v = chunks[t];
    int s = v;
#pragma unroll
    for (int off = 1; off < 64; off <<= 1) {
        const int u = __shfl_up(s, off);
        if (lane >= off) s += u;
    }
    if (lane == 63) ws[wv] = s;
    __syncthreads();
    if (t < 16) {
        const int u = ws[t];
        int ss = u;
#pragma unroll
        for (int off = 1; off < 16; off <<= 1) {
            const int uu = __shfl_up(ss, off);
            if (lane >= off) ss += uu;
        }
        ws[t] = ss - u;                             // exclusive over wave sums
    }
    __syncthreads();
    chunks[t] = s - v + ws[wv];                     // exclusive global scan
}

__global__ __launch_bounds__(256) void k_scanC(int* __restrict__ cursor,
                                               const int* __restrict__ chunks,
                                               int* __restrict__ rowptr)
{
    const int c = blockIdx.x * 256 + threadIdx.x;   // 0..1023
    const int n0 = c * CHUNK;
    const int n1 = min(n0 + CHUNK, NNODES);
    int run = chunks[c];
    for (int n = n0; n < n1; ++n) {
        const int d = cursor[n];                    // counts
        rowptr[n] = run;
        cursor[n] = run;                            // fill cursor start
        run += d;
    }
    if (n1 == NNODES && n0 < NNODES) rowptr[NNODES] = run;   // = NEDGES
}

__global__ __launch_bounds__(256) void k_fill(const int* __restrict__ ei,
                                              int* __restrict__ cursor,
                                              int* __restrict__ perm)
{
    const int e = blockIdx.x * 256 + threadIdx.x;
    const int pos = atomicAdd(&cursor[ei[e]], 1);
    perm[pos] = e;
}

// ---------------------------------------------------------------------------
// Gather: 2 waves per node (ch = tid&127). We column in 64 VGPRs. Per edge:
// broadcast (e,src) via shfl+readfirstlane -> eattr row becomes scalar loads;
// x[src] is a coalesced 256B/wave read (L3-hot). 4 FMA chains for ILP.
// Writes h = (1+eps)*x + sum(relu(...)) once -- no atomics, no memset.
// ---------------------------------------------------------------------------
__global__ __launch_bounds__(256) void k_gather(
    const float* __restrict__ x,
    const int* __restrict__ ei,
    const float* __restrict__ ea,
    const float* __restrict__ We,
    const float* __restrict__ be,
    const int* __restrict__ rowptr,
    const int* __restrict__ perm,
    const float* __restrict__ eps,
    float* __restrict__ h)
{
    const int tid  = threadIdx.x;
    const int ch   = tid & 127;
    const int lane = tid & 63;
    const int node = blockIdx.x * 2 + (tid >> 7);

    float w[EDIM];
#pragma unroll
    for (int k = 0; k < EDIM; ++k) w[k] = We[k * CIN + ch];
    const float bch = be[ch];

    const int r0 = __builtin_amdgcn_readfirstlane(rowptr[node]);
    const int r1 = __builtin_amdgcn_readfirstlane(rowptr[node + 1]);

    float acc = 0.0f;
    for (int base = r0; base < r1; base += 64) {
        const int nb = min(64, r1 - base);
        int ev = 0, sv = 0;
        if (lane < nb) {
            ev = perm[base + lane];
            sv = ei[NEDGES + ev];                    // src = edge_index[1][e]
        }
        for (int j = 0; j < nb; ++j) {
            const int e = __builtin_amdgcn_readfirstlane(__shfl(ev, j));
            const int s = __builtin_amdgcn_readfirstlane(__shfl(sv, j));
            const float xv = x[(size_t)s * CIN + ch];
            const float4* __restrict__ er = (const float4*)(ea + (size_t)e * EDIM);
            float p0 = bch, p1 = 0.f, p2 = 0.f, p3 = 0.f;
#pragma unroll
            for (int k4 = 0; k4 < EDIM / 4; ++k4) {
                const float4 v = er[k4];             // uniform -> scalar loads
                p0 = fmaf(v.x, w[4 * k4 + 0], p0);
                p1 = fmaf(v.y, w[4 * k4 + 1], p1);
                p2 = fmaf(v.z, w[4 * k4 + 2], p2);
                p3 = fmaf(v.w, w[4 * k4 + 3], p3);
            }
            acc += fmaxf(((p0 + p1) + (p2 + p3)) + xv, 0.0f);
        }
    }
    const float s1p = 1.0f + eps[0];
    const size_t o = (size_t)node * CIN + ch;
    h[o] = fmaf(s1p, x[o], acc);
}

// ---------------------------------------------------------------------------
// K2: h1 = relu(LN(h @ W1 + b1)) stored as bf16.
// Thread t = output channel t (256 ch). W1 column in 128 VGPRs.
// 32 nodes/block staged in LDS, processed in batches of 4.
// ---------------------------------------------------------------------------
__global__ __launch_bounds__(256) void k2_mlp1(
    const float* __restrict__ h,
    const float* __restrict__ W1,
    const float* __restrict__ b1,
    const float* __restrict__ gamma,
    const float* __restrict__ beta,
    __hip_bfloat16* __restrict__ h1)
{
    __shared__ float hs[32][CIN];      // 16 KB
    __shared__ float red[4][4][2];     // [wave][node-in-batch][sum,sumsq]
    const int t    = threadIdx.x;
    const int lane = t & 63;
    const int wv   = t >> 6;
    const int n0   = blockIdx.x * 32;

    {   // stage 32 h rows
        const float4* __restrict__ hg = (const float4*)(h + (size_t)n0 * CIN);
        float4* __restrict__ hl = (float4*)&hs[0][0];
#pragma unroll
        for (int i = 0; i < 4; ++i) hl[t + i * 256] = hg[t + i * 256];
    }

    float w1r[CIN];
#pragma unroll
    for (int k = 0; k < CIN; ++k) w1r[k] = W1[(size_t)k * C2 + t];
    const float b1r = b1[t], gr = gamma[t], br = beta[t];

    __syncthreads();

    for (int nb = 0; nb < 32; nb += 4) {
        float a0 = 0.f, a1 = 0.f, a2 = 0.f, a3 = 0.f;
        const float4* __restrict__ r0 = (const float4*)&hs[nb + 0][0];
        const float4* __restrict__ r1 = (const float4*)&hs[nb + 1][0];
        const float4* __restrict__ r2 = (const float4*)&hs[nb + 2][0];
        const float4* __restrict__ r3 = (const float4*)&hs[nb + 3][0];
#pragma unroll
        for (int k4 = 0; k4 < CIN / 4; ++k4) {
            const float4 v0 = r0[k4];                 // ds_read_b128 broadcast
            a0 = fmaf(v0.x, w1r[4*k4+0], a0);
            a0 = fmaf(v0.y, w1r[4*k4+1], a0);
            a0 = fmaf(v0.z, w1r[4*k4+2], a0);
            a0 = fmaf(v0.w, w1r[4*k4+3], a0);
            const float4 v1 = r1[k4];
            a1 = fmaf(v1.x, w1r[4*k4+0], a1);
            a1 = fmaf(v1.y, w1r[4*k4+1], a1);
            a1 = fmaf(v1.z, w1r[4*k4+2], a1);
            a1 = fmaf(v1.w, w1r[4*k4+3], a1);
            const float4 v2 = r2[k4];
            a2 = fmaf(v2.x, w1r[4*k4+0], a2);
            a2 = fmaf(v2.y, w1r[4*k4+1], a2);
            a2 = fmaf(v2.z, w1r[4*k4+2], a2);
            a2 = fmaf(v2.w, w1r[4*k4+3], a2);
            const float4 v3 = r3[k4];
            a3 = fmaf(v3.x, w1r[4*k4+0], a3);
            a3 = fmaf(v3.y, w1r[4*k4+1], a3);
            a3 = fmaf(v3.z, w1r[4*k4+2], a3);
            a3 = fmaf(v3.w, w1r[4*k4+3], a3);
        }
        a0 += b1r; a1 += b1r; a2 += b1r; a3 += b1r;

        float s0=a0, s1=a1, s2=a2, s3=a3;
        float q0=a0*a0, q1=a1*a1, q2=a2*a2, q3=a3*a3;
#pragma unroll
        for (int off = 32; off > 0; off >>= 1) {
            s0 += __shfl_xor(s0, off); q0 += __shfl_xor(q0, off);
            s1 += __shfl_xor(s1, off); q1 += __shfl_xor(q1, off);
            s2 += __shfl_xor(s2, off); q2 += __shfl_xor(q2, off);
            s3 += __shfl_xor(s3, off); q3 += __shfl_xor(q3, off);
        }
        if (lane == 0) {
            red[wv][0][0]=s0; red[wv][0][1]=q0;
            red[wv][1][0]=s1; red[wv][1][1]=q1;
            red[wv][2][0]=s2; red[wv][2][1]=q2;
            red[wv][3][0]=s3; red[wv][3][1]=q3;
        }
        __syncthreads();
        const float inv = 1.0f / 256.0f;
        {
            const float mu = (red[0][0][0]+red[1][0][0]+red[2][0][0]+red[3][0][0]) * inv;
            const float vv = (red[0][0][1]+red[1][0][1]+red[2][0][1]+red[3][0][1]) * inv - mu*mu;
            const float o  = fmaxf(fmaf((a0 - mu) * rsqrtf(vv + 1e-5f), gr, br), 0.f);
            h1[(size_t)(n0 + nb + 0) * C2 + t] = __float2bfloat16(o);
        }
        {
            const float mu = (red[0][1][0]+red[1][1][0]+red[2][1][0]+red[3][1][0]) * inv;
            const float vv = (red[0][1][1]+red[1][1][1]+red[2][1][1]+red[3][1][1]) * inv - mu*mu;
            const float o  = fmaxf(fmaf((a1 - mu) * rsqrtf(vv + 1e-5f), gr, br), 0.f);
            h1[(size_t)(n0 + nb + 1) * C2 + t] = __float2bfloat16(o);
        }
        {
            const float mu = (red[0][2][0]+red[1][2][0]+red[2][2][0]+red[3][2][0]) * inv;
            const float vv = (red[0][2][1]+red[1][2][1]+red[2][2][1]+red[3][2][1]) * inv - mu*mu;
            const float o  = fmaxf(fmaf((a2 - mu) * rsqrtf(vv + 1e-5f), gr, br), 0.f);
            h1[(size_t)(n0 + nb + 2) * C2 + t] = __float2bfloat16(o);
        }
        {
            const float mu = (red[0][3][0]+red[1][3][0]+red[2][3][0]+red[3][3][0]) * inv;
            const float vv = (red[0][3][1]+red[1][3][1]+red[2][3][1]+red[3][3][1]) * inv - mu*mu;
            const float o  = fmaxf(fmaf((a3 - mu) * rsqrtf(vv + 1e-5f), gr, br), 0.f);
            h1[(size_t)(n0 + nb + 3) * C2 + t] = __float2bfloat16(o);
        }
        __syncthreads();   // protect red[] before next batch
    }
}

// ---------------------------------------------------------------------------
// K3: out = h1 @ W2 + b2.  Thread t -> (j = t&127 out channel, half = t>>7 k-half).
// W2 half-column in 128 VGPRs. 32 nodes/block staged (bf16->f32) in LDS.
// ---------------------------------------------------------------------------
__global__ __launch_bounds__(256) void k3_mlp2(
    const __hip_bfloat16* __restrict__ h1,
    const float* __restrict__ W2,
    const float* __restrict__ b2,
    float* __restrict__ out)
{
    __shared__ float hsf[32 * C2];     // 32 KB
    __shared__ float pbuf[4][CIN];     // 2 KB
    const int t    = threadIdx.x;
    const int j    = t & 127;
    const int half = t >> 7;
    const int n0   = blockIdx.x * 32;

    float w2r[CIN];
#pragma unroll
    for (int k = 0; k < CIN; ++k)
        w2r[k] = W2[(size_t)(half * CIN + k) * CIN + j];
    const float b2r = b2[j];

    {   // stage 32 rows of h1 (bf16) as f32
        const uint32_t* __restrict__ hg = (const uint32_t*)(h1 + (size_t)n0 * C2);
#pragma unroll
        for (int i = 0; i < 16; ++i) {
            const uint32_t u = hg[t + i * 256];
            const int idx = 2 * (t + i * 256);
            hsf[idx]     = __uint_as_float(u << 16);
            hsf[idx + 1] = __uint_as_float(u & 0xffff0000u);
        }
    }
    __syncthreads();

    for (int nb = 0; nb < 32; nb += 4) {
        float p0 = 0.f, p1 = 0.f, p2 = 0.f, p3 = 0.f;
        const float4* __restrict__ r0 = (const float4*)&hsf[(nb+0)*C2 + half*CIN];
        const float4* __restrict__ r1 = (const float4*)&hsf[(nb+1)*C2 + half*CIN];
        const float4* __restrict__ r2 = (const float4*)&hsf[(nb+2)*C2 + half*CIN];
        const float4* __restrict__ r3 = (const float4*)&hsf[(nb+3)*C2 + half*CIN];
#pragma unroll
        for (int k4 = 0; k4 < CIN / 4; ++k4) {
            const float4 v0 = r0[k4];
            p0 = fmaf(v0.x, w2r[4*k4+0], p0);
            p0 = fmaf(v0.y, w2r[4*k4+1], p0);
            p0 = fmaf(v0.z, w2r[4*k4+2], p0);
            p0 = fmaf(v0.w, w2r[4*k4+3], p0);
            const float4 v1 = r1[k4];
            p1 = fmaf(v1.x, w2r[4*k4+0], p1);
            p1 = fmaf(v1.y, w2r[4*k4+1], p1);
            p1 = fmaf(v1.z, w2r[4*k4+2], p1);
            p1 = fmaf(v1.w, w2r[4*k4+3], p1);
            const float4 v2 = r2[k4];
            p2 = fmaf(v2.x, w2r[4*k4+0], p2);
            p2 = fmaf(v2.y, w2r[4*k4+1], p2);
            p2 = fmaf(v2.z, w2r[4*k4+2], p2);
            p2 = fmaf(v2.w, w2r[4*k4+3], p2);
            const float4 v3 = r3[k4];
            p3 = fmaf(v3.x, w2r[4*k4+0], p3);
            p3 = fmaf(v3.y, w2r[4*k4+1], p3);
            p3 = fmaf(v3.z, w2r[4*k4+2], p3);
            p3 = fmaf(v3.w, w2r[4*k4+3], p3);
        }
        if (half) {
            pbuf[0][j] = p0; pbuf[1][j] = p1; pbuf[2][j] = p2; pbuf[3][j] = p3;
        }
        __syncthreads();
        if (!half) {
            out[(size_t)(n0+nb+0)*CIN + j] = p0 + pbuf[0][j] + b2r;
            out[(size_t)(n0+nb+1)*CIN + j] = p1 + pbuf[1][j] + b2r;
            out[(size_t)(n0+nb+2)*CIN + j] = p2 + pbuf[2][j] + b2r;
            out[(size_t)(n0+nb+3)*CIN + j] = p3 + pbuf[3][j] + b2r;
        }
        __syncthreads();
    }
}

// ---------------------------------------------------------------------------
extern "C" void kernel_launch(void* const* d_in, const int* in_sizes, int n_in,
                              void* d_out, int out_size, void* d_ws, size_t ws_size,
                              hipStream_t stream)
{
    const float* x     = (const float*)d_in[0];
    const int*   ei    = (const int*)d_in[1];
    const float* ea    = (const float*)d_in[2];
    const float* We    = (const float*)d_in[3];
    const float* be    = (const float*)d_in[4];
    const float* W1    = (const float*)d_in[5];
    const float* b1    = (const float*)d_in[6];
    const float* gamma = (const float*)d_in[7];
    const float* beta  = (const float*)d_in[8];
    const float* W2    = (const float*)d_in[9];
    const float* b2    = (const float*)d_in[10];
    const float* eps   = (const float*)d_in[11];

    // ws layout: [h f32 51.2MB][overlay: h1 bf16 51.2MB | CSR scratch 3.4MB]
    // CSR scratch is consumed before k2 writes h1 -> safe overlay.
    char* wsB = (char*)d_ws;
    float* h = (float*)wsB;                                   // 51,200,000 B
    char* ovl = wsB + (size_t)NNODES * CIN * 4;
    __hip_bfloat16* h1 = (__hip_bfloat16*)ovl;                // 51,200,000 B
    int* rowptr = (int*)ovl;                                  // 400,004 B
    int* cursor = (int*)(ovl + 400016);                       // 400,000 B
    int* perm   = (int*)(ovl + 800032);                       // 2,560,000 B
    int* chunks = (int*)(ovl + 3360032);                      // 4,096 B

    hipMemsetAsync(cursor, 0, NNODES * sizeof(int), stream);
    k_hist <<<NEDGES / 256, 256, 0, stream>>>(ei, cursor);
    k_scanA<<<4, 256, 0, stream>>>(cursor, chunks);
    k_scanB<<<1, 1024, 0, stream>>>(chunks);
    k_scanC<<<4, 256, 0, stream>>>(cursor, chunks, rowptr);
    k_fill <<<NEDGES / 256, 256, 0, stream>>>(ei, cursor, perm);
    k_gather<<<NNODES / 2, 256, 0, stream>>>(x, ei, ea, We, be, rowptr, perm, eps, h);
    k2_mlp1<<<NNODES / 32, 256, 0, stream>>>(h, W1, b1, gamma, beta, h1);
    k3_mlp2<<<NNODES / 32, 256, 0, stream>>>(h1, W2, b2, (float*)d_out);
}

// Round 3
// 428.321 us; speedup vs baseline: 2.4402x; 2.0955x over previous
//
#include <hip/hip_runtime.h>
#include <hip/hip_bf16.h>
#include <stdint.h>

#define NNODES 100000
#define NEDGES 640000
#define CIN 128
#define EDIM 64
#define C2 256
#define EB 320000          // edges per msg batch
#define LN_EPS 1e-5f

typedef __attribute__((ext_vector_type(8))) short bf16x8;
typedef __attribute__((ext_vector_type(4))) float f32x4;

__device__ __forceinline__ ushort f2bf(float f) {
    uint32_t u = __float_as_uint(f);
    uint32_t r = (u + 0x7fffu + ((u >> 16) & 1u)) >> 16;   // RNE
    return (ushort)r;
}
__device__ __forceinline__ float bf2f_lo(uint32_t u) { return __uint_as_float(u << 16); }
__device__ __forceinline__ float bf2f_hi(uint32_t u) { return __uint_as_float(u & 0xffff0000u); }

union U16 { uint4 u; bf16x8 v; };

// ---------------------------------------------------------------------------
// CSR build: histogram -> 2-level exclusive scan -> fill (perm + sorted src).
// ---------------------------------------------------------------------------
__global__ __launch_bounds__(256) void k_hist(const int* __restrict__ ei,
                                              int* __restrict__ counts)
{
    const int e = blockIdx.x * 256 + threadIdx.x;
    atomicAdd(&counts[ei[e]], 1);
}

#define CHUNK 98   // 1024 * 98 >= 100000

__global__ __launch_bounds__(256) void k_scanA(const int* __restrict__ counts,
                                               int* __restrict__ chunks)
{
    const int c = blockIdx.x * 256 + threadIdx.x;
    const int n0 = c * CHUNK;
    const int n1 = min(n0 + CHUNK, NNODES);
    int s = 0;
    for (int n = n0; n < n1; ++n) s += counts[n];
    chunks[c] = s;
}

__global__ __launch_bounds__(1024) void k_scanB(int* __restrict__ chunks)
{
    __shared__ int ws[16];
    const int t = threadIdx.x, lane = t & 63, wv = t >> 6;
    const int v = chunks[t];
    int s = v;
#pragma unroll
    for (int off = 1; off < 64; off <<= 1) {
        const int u = __shfl_up(s, off);
        if (lane >= off) s += u;
    }
    if (lane == 63) ws[wv] = s;
    __syncthreads();
    if (t < 16) {
        const int u = ws[t];
        int ss = u;
#pragma unroll
        for (int off = 1; off < 16; off <<= 1) {
            const int uu = __shfl_up(ss, off);
            if (lane >= off) ss += uu;
        }
        ws[t] = ss - u;
    }
    __syncthreads();
    chunks[t] = s - v + ws[wv];
}

__global__ __launch_bounds__(256) void k_scanC(int* __restrict__ cursor,
                                               const int* __restrict__ chunks,
                                               int* __restrict__ rowptr)
{
    const int c = blockIdx.x * 256 + threadIdx.x;
    const int n0 = c * CHUNK;
    const int n1 = min(n0 + CHUNK, NNODES);
    int run = chunks[c];
    for (int n = n0; n < n1; ++n) {
        const int d = cursor[n];
        rowptr[n] = run;
        cursor[n] = run;
        run += d;
    }
    if (n1 == NNODES && n0 < NNODES) rowptr[NNODES] = run;
}

__global__ __launch_bounds__(256) void k_fill(const int* __restrict__ ei,
                                              int* __restrict__ cursor,
                                              int* __restrict__ perm,
                                              int* __restrict__ srcS)
{
    const int e = blockIdx.x * 256 + threadIdx.x;
    const int pos = atomicAdd(&cursor[ei[e]], 1);
    perm[pos] = e;
    srcS[pos] = ei[NEDGES + e];
}

// ---------------------------------------------------------------------------
// Edge GEMM (bf16 MFMA): msgS[p] = ea[perm[B0+p]] @ We, sorted order, bf16.
// Wave = 16 positions x 128 cols = 16 MFMA (8 col-tiles x 2 K-steps).
// A: lane supplies ea[row=l&15][k=(l>>4)*8+j]; B frags held in 64 VGPRs.
// ---------------------------------------------------------------------------
__global__ __launch_bounds__(256) void k_emsg(
    const float* __restrict__ ea, const float* __restrict__ We,
    const int* __restrict__ perm, ushort* __restrict__ msgS, int B0)
{
    const int l   = threadIdx.x & 63;
    const int q   = l >> 4;
    const int m16 = l & 15;
    const int gw  = blockIdx.x * 4 + (threadIdx.x >> 6);
    const int nw  = gridDim.x * 4;

    bf16x8 bf[2][8];
#pragma unroll
    for (int ks = 0; ks < 2; ++ks)
#pragma unroll
        for (int t = 0; t < 8; ++t) {
            const int c = m16 + 16 * t;
#pragma unroll
            for (int j = 0; j < 8; ++j) {
                const int k = ks * 32 + q * 8 + j;
                bf[ks][t][j] = (short)f2bf(We[k * CIN + c]);
            }
        }

    const int NT = EB / 16;                       // 20000 tiles per batch
    for (int tt = gw; tt < NT; tt += nw) {
        const int p0 = B0 + tt * 16;
        const int ep = perm[p0 + m16];            // this lane's A row
        f32x4 acc[8];
#pragma unroll
        for (int t = 0; t < 8; ++t) acc[t] = (f32x4){0.f, 0.f, 0.f, 0.f};
#pragma unroll
        for (int ks = 0; ks < 2; ++ks) {
            const float* ar = ea + (size_t)ep * EDIM + ks * 32 + q * 8;
            const float4 f0 = *(const float4*)ar;
            const float4 f1 = *(const float4*)(ar + 4);
            bf16x8 a;
            a[0] = (short)f2bf(f0.x); a[1] = (short)f2bf(f0.y);
            a[2] = (short)f2bf(f0.z); a[3] = (short)f2bf(f0.w);
            a[4] = (short)f2bf(f1.x); a[5] = (short)f2bf(f1.y);
            a[6] = (short)f2bf(f1.z); a[7] = (short)f2bf(f1.w);
#pragma unroll
            for (int t = 0; t < 8; ++t)
                acc[t] = __builtin_amdgcn_mfma_f32_16x16x32_bf16(a, bf[ks][t], acc[t], 0, 0, 0);
        }
        // D: lane l, reg r -> row q*4+r, col m16+16t
        ushort* mrow = msgS + (size_t)(tt * 16 + q * 4) * CIN + m16;
#pragma unroll
        for (int t = 0; t < 8; ++t)
#pragma unroll
            for (int r = 0; r < 4; ++r)
                mrow[(size_t)r * CIN + 16 * t] = f2bf(acc[t][r]);
    }
}

// ---------------------------------------------------------------------------
// Gather-sum: 1 wave/node, 2 channels/lane. msgS rows are contiguous (sorted),
// x[src] rows wave-uniform. h (bf16-packed) accumulated across 2 batches.
// ---------------------------------------------------------------------------
__global__ __launch_bounds__(256) void k_gsum(
    const float* __restrict__ x, const int* __restrict__ srcS,
    const ushort* __restrict__ msgS, const float* __restrict__ be,
    const int* __restrict__ rowptr, const float* __restrict__ eps,
    uint32_t* __restrict__ hbf, int B0, int B1, int first)
{
    const int lane = threadIdx.x & 63;
    const int node = blockIdx.x * 4 + (threadIdx.x >> 6);
    const int r0 = rowptr[node], r1 = rowptr[node + 1];
    const int c0 = max(r0, B0), c1 = min(r1, B1);

    const size_t ho = (size_t)node * 64 + lane;
    float a0, a1;
    if (first) {
        const float s1p = 1.0f + eps[0];
        const float2 xv = ((const float2*)x)[ho];
        a0 = s1p * xv.x; a1 = s1p * xv.y;
    } else {
        if (c0 >= c1) return;
        const uint32_t hv = hbf[ho];
        a0 = bf2f_lo(hv); a1 = bf2f_hi(hv);
    }
    const float2 b2v = ((const float2*)be)[lane];
    const uint32_t* msg2 = (const uint32_t*)msgS;

    for (int base = c0; base < c1; base += 64) {
        const int nb = min(64, c1 - base);
        const int sv = (lane < nb) ? srcS[base + lane] : 0;
        for (int j = 0; j < nb; ++j) {
            const int s = __builtin_amdgcn_readfirstlane(__shfl(sv, j));
            const uint32_t m2 = msg2[(size_t)(base + j - B0) * 64 + lane];
            const float2 xs = ((const float2*)x)[(size_t)s * 64 + lane];
            a0 += fmaxf(xs.x + bf2f_lo(m2) + b2v.x, 0.0f);
            a1 += fmaxf(xs.y + bf2f_hi(m2) + b2v.y, 0.0f);
        }
    }
    hbf[ho] = (uint32_t)f2bf(a0) | ((uint32_t)f2bf(a1) << 16);
}

// ---------------------------------------------------------------------------
// K2: h1 = relu(LN(h @ W1 + b1)) bf16.  8 waves x 16 rows = 128 rows/block.
// W1^T bf16 in LDS, XOR-swizzled (byte ^= (c&7)<<4). A read direct from hbf.
// LN via 16-lane shfl_xor on the (col=l&15,row=(l>>4)*4+r) D layout.
// ---------------------------------------------------------------------------
__global__ __launch_bounds__(512, 2) void k2_mfma(
    const uint32_t* __restrict__ hbf, const float* __restrict__ W1,
    const float* __restrict__ b1, const float* __restrict__ gamma,
    const float* __restrict__ beta, ushort* __restrict__ h1)
{
    __shared__ ushort w1t[CIN * C2];      // [c][k] swizzled, 64 KB
    __shared__ float b1s[C2], gs[C2], bs[C2];

    const int tid = threadIdx.x;
    for (int i = tid; i < CIN * C2; i += 512) {     // W1[k][c] -> W1T
        const int k = i >> 8, c = i & 255;
        const int byte = (2 * k) ^ ((c & 7) << 4);
        *(ushort*)((char*)w1t + (size_t)c * 256 + byte) = f2bf(W1[i]);
    }
    if (tid < C2) { b1s[tid] = b1[tid]; gs[tid] = gamma[tid]; bs[tid] = beta[tid]; }
    __syncthreads();

    const int l = tid & 63, q = l >> 4, m16 = l & 15;
    const int w = tid >> 6;
    const int n0 = blockIdx.x * 128 + w * 16;
    const int rowA = min(n0 + m16, NNODES - 1);

    f32x4 acc[16];
#pragma unroll
    for (int t = 0; t < 16; ++t) acc[t] = (f32x4){0.f, 0.f, 0.f, 0.f};

    const char* w1b = (const char*)w1t;
#pragma unroll
    for (int ks = 0; ks < 4; ++ks) {
        U16 A; A.u = *(const uint4*)((const char*)hbf + (size_t)rowA * 256 + ks * 64 + q * 16);
        const int inrow = (ks * 64 + q * 16) ^ ((l & 7) << 4);
#pragma unroll
        for (int t = 0; t < 16; ++t) {
            const int c = m16 + 16 * t;
            U16 B; B.u = *(const uint4*)(w1b + (size_t)c * 256 + inrow);
            acc[t] = __builtin_amdgcn_mfma_f32_16x16x32_bf16(A.v, B.v, acc[t], 0, 0, 0);
        }
    }

    float s[4] = {0.f, 0.f, 0.f, 0.f}, sq[4] = {0.f, 0.f, 0.f, 0.f};
#pragma unroll
    for (int t = 0; t < 16; ++t) {
        const float bb = b1s[m16 + 16 * t];
#pragma unroll
        for (int r = 0; r < 4; ++r) {
            acc[t][r] += bb;
            s[r]  += acc[t][r];
            sq[r] += acc[t][r] * acc[t][r];
        }
    }
#pragma unroll
    for (int off = 1; off < 16; off <<= 1)
#pragma unroll
        for (int r = 0; r < 4; ++r) {
            s[r]  += __shfl_xor(s[r],  off);
            sq[r] += __shfl_xor(sq[r], off);
        }
    float mu[4], is[4];
#pragma unroll
    for (int r = 0; r < 4; ++r) {
        mu[r] = s[r] * (1.0f / 256.0f);
        const float var = sq[r] * (1.0f / 256.0f) - mu[r] * mu[r];
        is[r] = rsqrtf(var + LN_EPS);
    }
#pragma unroll
    for (int t = 0; t < 16; ++t) {
        const int c = m16 + 16 * t;
        const float g = gs[c], b = bs[c];
#pragma unroll
        for (int r = 0; r < 4; ++r) {
            const int row = n0 + q * 4 + r;
            if (row < NNODES) {
                const float o = fmaxf((acc[t][r] - mu[r]) * is[r] * g + b, 0.0f);
                h1[(size_t)row * C2 + c] = f2bf(o);
            }
        }
    }
}

// ---------------------------------------------------------------------------
// K3: out = h1 @ W2 + b2 (f32). Same structure, N=128, K=256.
// ---------------------------------------------------------------------------
__global__ __launch_bounds__(512, 2) void k3_mfma(
    const ushort* __restrict__ h1, const float* __restrict__ W2,
    const float* __restrict__ b2, float* __restrict__ out)
{
    __shared__ ushort w2t[C2 * CIN];      // [c(128)][k(256)] swizzled, 64 KB
    const int tid = threadIdx.x;
    for (int i = tid; i < C2 * CIN; i += 512) {     // W2[k][c] -> W2T
        const int k = i >> 7, c = i & 127;
        const int byte = (2 * k) ^ ((c & 7) << 4);
        *(ushort*)((char*)w2t + (size_t)c * 512 + byte) = f2bf(W2[i]);
    }
    __syncthreads();

    const int l = tid & 63, q = l >> 4, m16 = l & 15;
    const int w = tid >> 6;
    const int n0 = blockIdx.x * 128 + w * 16;
    const int rowA = min(n0 + m16, NNODES - 1);

    f32x4 acc[8];
#pragma unroll
    for (int t = 0; t < 8; ++t) acc[t] = (f32x4){0.f, 0.f, 0.f, 0.f};

    const char* w2b = (const char*)w2t;
#pragma unroll
    for (int ks = 0; ks < 8; ++ks) {
        U16 A; A.u = *(const uint4*)((const char*)h1 + (size_t)rowA * 512 + ks * 64 + q * 16);
        const int inrow = (ks * 64 + q * 16) ^ ((l & 7) << 4);
#pragma unroll
        for (int t = 0; t < 8; ++t) {
            const int c = m16 + 16 * t;
            U16 B; B.u = *(const uint4*)(w2b + (size_t)c * 512 + inrow);
            acc[t] = __builtin_amdgcn_mfma_f32_16x16x32_bf16(A.v, B.v, acc[t], 0, 0, 0);
        }
    }
#pragma unroll
    for (int t = 0; t < 8; ++t) {
        const int c = m16 + 16 * t;
        const float bb = b2[c];
#pragma unroll
        for (int r = 0; r < 4; ++r) {
            const int row = n0 + q * 4 + r;
            if (row < NNODES)
                out[(size_t)row * CIN + c] = acc[t][r] + bb;
        }
    }
}

// ---------------------------------------------------------------------------
extern "C" void kernel_launch(void* const* d_in, const int* in_sizes, int n_in,
                              void* d_out, int out_size, void* d_ws, size_t ws_size,
                              hipStream_t stream)
{
    const float* x     = (const float*)d_in[0];
    const int*   ei    = (const int*)d_in[1];
    const float* ea    = (const float*)d_in[2];
    const float* We    = (const float*)d_in[3];
    const float* be    = (const float*)d_in[4];
    const float* W1    = (const float*)d_in[5];
    const float* b1    = (const float*)d_in[6];
    const float* gamma = (const float*)d_in[7];
    const float* beta  = (const float*)d_in[8];
    const float* W2    = (const float*)d_in[9];
    const float* b2    = (const float*)d_in[10];
    const float* eps   = (const float*)d_in[11];

    // ws layout (all offsets 512-aligned), total ~113.5 MB:
    char* wsB = (char*)d_ws;
    uint32_t* hbf   = (uint32_t*)wsB;                       // 25,600,000 B (h bf16-packed)
    int* rowptr = (int*)(wsB + 25600000);                   //    400,004 B
    int* cursor = (int*)(wsB + 26000512);                   //    400,000 B
    int* perm   = (int*)(wsB + 26401024);                   //  2,560,000 B
    int* srcS   = (int*)(wsB + 28961024);                   //  2,560,000 B
    int* chunks = (int*)(wsB + 31521024);                   //      4,096 B
    ushort* msgS = (ushort*)(wsB + 31525120);               // 81,920,000 B
    ushort* h1   = (ushort*)msgS;                           // 51.2 MB, aliases msgS (dead by then)

    hipMemsetAsync(cursor, 0, NNODES * sizeof(int), stream);
    k_hist <<<NEDGES / 256, 256, 0, stream>>>(ei, cursor);
    k_scanA<<<4, 256, 0, stream>>>(cursor, chunks);
    k_scanB<<<1, 1024, 0, stream>>>(chunks);
    k_scanC<<<4, 256, 0, stream>>>(cursor, chunks, rowptr);
    k_fill <<<NEDGES / 256, 256, 0, stream>>>(ei, cursor, perm, srcS);

    for (int b = 0; b < 2; ++b) {
        const int B0 = b * EB;
        k_emsg<<<1280, 256, 0, stream>>>(ea, We, perm, msgS, B0);
        k_gsum<<<NNODES / 4, 256, 0, stream>>>(x, srcS, msgS, be, rowptr, eps,
                                               hbf, B0, B0 + EB, b == 0);
    }
    k2_mfma<<<(NNODES + 127) / 128, 512, 0, stream>>>(hbf, W1, b1, gamma, beta, h1);
    k3_mfma<<<(NNODES + 127) / 128, 512, 0, stream>>>(h1, W2, b2, (float*)d_out);
}

// Round 4
// 421.495 us; speedup vs baseline: 2.4797x; 1.0162x over previous
//
#include <hip/hip_runtime.h>
#include <hip/hip_bf16.h>
#include <stdint.h>

#define NNODES 100000
#define NEDGES 640000
#define CIN 128
#define EDIM 64
#define C2 256
#define LN_EPS 1e-5f

typedef __attribute__((ext_vector_type(8))) short bf16x8;
typedef __attribute__((ext_vector_type(4))) float f32x4;

__device__ __forceinline__ ushort f2bf(float f) {
    uint32_t u = __float_as_uint(f);
    uint32_t r = (u + 0x7fffu + ((u >> 16) & 1u)) >> 16;   // RNE
    return (ushort)r;
}
__device__ __forceinline__ float bf2f_lo(uint32_t u) { return __uint_as_float(u << 16); }
__device__ __forceinline__ float bf2f_hi(uint32_t u) { return __uint_as_float(u & 0xffff0000u); }

union U16 { uint4 u; bf16x8 v; };

// ---------------------------------------------------------------------------
// Zero the cursor array on the compute queue (graph-captured memset nodes go
// through the blit path: ~91us of queue-switch serialization -- measured r3).
// ---------------------------------------------------------------------------
__global__ __launch_bounds__(256) void k_zero(int* __restrict__ p)
{
    const int i = blockIdx.x * 256 + threadIdx.x;
    if (i < NNODES) p[i] = 0;
}

// ---------------------------------------------------------------------------
// CSR build: histogram -> 2-level exclusive scan -> fill (perm + sorted src).
// ---------------------------------------------------------------------------
__global__ __launch_bounds__(256) void k_hist(const int* __restrict__ ei,
                                              int* __restrict__ counts)
{
    const int e = blockIdx.x * 256 + threadIdx.x;
    atomicAdd(&counts[ei[e]], 1);
}

#define CHUNK 98   // 1024 * 98 >= 100000

__global__ __launch_bounds__(256) void k_scanA(const int* __restrict__ counts,
                                               int* __restrict__ chunks)
{
    const int c = blockIdx.x * 256 + threadIdx.x;
    const int n0 = c * CHUNK;
    const int n1 = min(n0 + CHUNK, NNODES);
    int s = 0;
    for (int n = n0; n < n1; ++n) s += counts[n];
    chunks[c] = s;
}

__global__ __launch_bounds__(1024) void k_scanB(int* __restrict__ chunks)
{
    __shared__ int ws[16];
    const int t = threadIdx.x, lane = t & 63, wv = t >> 6;
    const int v = chunks[t];
    int s = v;
#pragma unroll
    for (int off = 1; off < 64; off <<= 1) {
        const int u = __shfl_up(s, off);
        if (lane >= off) s += u;
    }
    if (lane == 63) ws[wv] = s;
    __syncthreads();
    if (t < 16) {
        const int u = ws[t];
        int ss = u;
#pragma unroll
        for (int off = 1; off < 16; off <<= 1) {
            const int uu = __shfl_up(ss, off);
            if (lane >= off) ss += uu;
        }
        ws[t] = ss - u;
    }
    __syncthreads();
    chunks[t] = s - v + ws[wv];
}

__global__ __launch_bounds__(256) void k_scanC(int* __restrict__ cursor,
                                               const int* __restrict__ chunks,
                                               int* __restrict__ rowptr)
{
    const int c = blockIdx.x * 256 + threadIdx.x;
    const int n0 = c * CHUNK;
    const int n1 = min(n0 + CHUNK, NNODES);
    int run = chunks[c];
    for (int n = n0; n < n1; ++n) {
        const int d = cursor[n];
        rowptr[n] = run;
        cursor[n] = run;
        run += d;
    }
    if (n1 == NNODES && n0 < NNODES) rowptr[NNODES] = run;
}

__global__ __launch_bounds__(256) void k_fill(const int* __restrict__ ei,
                                              int* __restrict__ cursor,
                                              int* __restrict__ perm,
                                              int* __restrict__ srcS)
{
    const int e = blockIdx.x * 256 + threadIdx.x;
    const int pos = atomicAdd(&cursor[ei[e]], 1);
    perm[pos] = e;
    srcS[pos] = ei[NEDGES + e];
}

// ---------------------------------------------------------------------------
// Edge GEMM (bf16 MFMA): msgS[p] = ea[perm[p]] @ We, sorted order, bf16.
// Wave = 16 positions x 128 cols = 16 MFMA. B frags in 64 VGPRs.
// ---------------------------------------------------------------------------
__global__ __launch_bounds__(256) void k_emsg(
    const float* __restrict__ ea, const float* __restrict__ We,
    const int* __restrict__ perm, ushort* __restrict__ msgS)
{
    const int l   = threadIdx.x & 63;
    const int q   = l >> 4;
    const int m16 = l & 15;
    const int gw  = blockIdx.x * 4 + (threadIdx.x >> 6);
    const int nw  = gridDim.x * 4;

    bf16x8 bf[2][8];
#pragma unroll
    for (int ks = 0; ks < 2; ++ks)
#pragma unroll
        for (int t = 0; t < 8; ++t) {
            const int c = m16 + 16 * t;
#pragma unroll
            for (int j = 0; j < 8; ++j) {
                const int k = ks * 32 + q * 8 + j;
                bf[ks][t][j] = (short)f2bf(We[k * CIN + c]);
            }
        }

    const int NT = NEDGES / 16;                   // 40000 tiles
    for (int tt = gw; tt < NT; tt += nw) {
        const int ep = perm[tt * 16 + m16];       // this lane's A row
        f32x4 acc[8];
#pragma unroll
        for (int t = 0; t < 8; ++t) acc[t] = (f32x4){0.f, 0.f, 0.f, 0.f};
#pragma unroll
        for (int ks = 0; ks < 2; ++ks) {
            const float* ar = ea + (size_t)ep * EDIM + ks * 32 + q * 8;
            const float4 f0 = *(const float4*)ar;
            const float4 f1 = *(const float4*)(ar + 4);
            bf16x8 a;
            a[0] = (short)f2bf(f0.x); a[1] = (short)f2bf(f0.y);
            a[2] = (short)f2bf(f0.z); a[3] = (short)f2bf(f0.w);
            a[4] = (short)f2bf(f1.x); a[5] = (short)f2bf(f1.y);
            a[6] = (short)f2bf(f1.z); a[7] = (short)f2bf(f1.w);
#pragma unroll
            for (int t = 0; t < 8; ++t)
                acc[t] = __builtin_amdgcn_mfma_f32_16x16x32_bf16(a, bf[ks][t], acc[t], 0, 0, 0);
        }
        ushort* mrow = msgS + (size_t)(tt * 16 + q * 4) * CIN + m16;
#pragma unroll
        for (int t = 0; t < 8; ++t)
#pragma unroll
            for (int r = 0; r < 4; ++r)
                mrow[(size_t)r * CIN + 16 * t] = f2bf(acc[t][r]);
    }
}

// ---------------------------------------------------------------------------
// Gather-sum: 1 wave/node, 2 channels/lane. msgS rows contiguous (sorted),
// x[src] rows wave-uniform. Writes h bf16-packed once.
// ---------------------------------------------------------------------------
__global__ __launch_bounds__(256) void k_gsum(
    const float* __restrict__ x, const int* __restrict__ srcS,
    const ushort* __restrict__ msgS, const float* __restrict__ be,
    const int* __restrict__ rowptr, const float* __restrict__ eps,
    uint32_t* __restrict__ hbf)
{
    const int lane = threadIdx.x & 63;
    const int node = blockIdx.x * 4 + (threadIdx.x >> 6);
    const int r0 = rowptr[node], r1 = rowptr[node + 1];

    const size_t ho = (size_t)node * 64 + lane;
    const float s1p = 1.0f + eps[0];
    const float2 xv = ((const float2*)x)[ho];
    float a0 = s1p * xv.x, a1 = s1p * xv.y;

    const float2 b2v = ((const float2*)be)[lane];
    const uint32_t* msg2 = (const uint32_t*)msgS;

    for (int base = r0; base < r1; base += 64) {
        const int nb = min(64, r1 - base);
        const int sv = (lane < nb) ? srcS[base + lane] : 0;
        for (int j = 0; j < nb; ++j) {
            const int s = __builtin_amdgcn_readfirstlane(__shfl(sv, j));
            const uint32_t m2 = msg2[(size_t)(base + j) * 64 + lane];
            const float2 xs = ((const float2*)x)[(size_t)s * 64 + lane];
            a0 += fmaxf(xs.x + bf2f_lo(m2) + b2v.x, 0.0f);
            a1 += fmaxf(xs.y + bf2f_hi(m2) + b2v.y, 0.0f);
        }
    }
    hbf[ho] = (uint32_t)f2bf(a0) | ((uint32_t)f2bf(a1) << 16);
}

// ---------------------------------------------------------------------------
// Fused MLP: out = relu(LN(h@W1+b1))@W2 + b2, h1 never leaves LDS.
// 8 waves x 16 rows = 128 rows/block. W1^T, W2^T bf16 in LDS with
// byte ^= (c&15)<<4 swizzle (16-slot spread -> conflict-free b128).
// After GEMM1+LN+ReLU each wave writes its 16x256 h1 tile into the (dead)
// w1t region and runs GEMM2 from LDS. Saves the 102MB h1 round-trip.
// ---------------------------------------------------------------------------
__global__ __launch_bounds__(512, 2) void k23_fused(
    const uint32_t* __restrict__ hbf, const float* __restrict__ W1,
    const float* __restrict__ b1, const float* __restrict__ gamma,
    const float* __restrict__ beta, const float* __restrict__ W2,
    const float* __restrict__ b2, float* __restrict__ out)
{
    __shared__ ushort w1t[CIN * C2];      // 64 KB  (later: h1 tiles, 8KB/wave)
    __shared__ ushort w2t[C2 * CIN];      // 64 KB
    __shared__ float b1s[C2], gs[C2], bs[C2];

    const int tid = threadIdx.x;
    for (int i = tid; i < CIN * C2; i += 512) {     // W1[k][c] -> W1T swizzled
        const int k = i >> 8, c = i & 255;
        *(ushort*)((char*)w1t + (size_t)c * 256 + ((2 * k) ^ ((c & 15) << 4))) = f2bf(W1[i]);
    }
    for (int i = tid; i < C2 * CIN; i += 512) {     // W2[k][c] -> W2T swizzled
        const int k = i >> 7, c = i & 127;
        *(ushort*)((char*)w2t + (size_t)c * 512 + ((2 * k) ^ ((c & 15) << 4))) = f2bf(W2[i]);
    }
    if (tid < C2) { b1s[tid] = b1[tid]; gs[tid] = gamma[tid]; bs[tid] = beta[tid]; }
    __syncthreads();

    const int l = tid & 63, q = l >> 4, m16 = l & 15;
    const int w = tid >> 6;
    const int n0 = blockIdx.x * 128 + w * 16;
    const int rowA = min(n0 + m16, NNODES - 1);

    // ---- GEMM1: [16 x 128] @ [128 x 256] ----
    f32x4 acc[16];
#pragma unroll
    for (int t = 0; t < 16; ++t) acc[t] = (f32x4){0.f, 0.f, 0.f, 0.f};

    const char* w1b = (const char*)w1t;
#pragma unroll
    for (int ks = 0; ks < 4; ++ks) {
        U16 A; A.u = *(const uint4*)((const char*)hbf + (size_t)rowA * 256 + ks * 64 + q * 16);
        const int inrow = (ks * 64 + q * 16) ^ (m16 << 4);
#pragma unroll
        for (int t = 0; t < 16; ++t) {
            U16 B; B.u = *(const uint4*)(w1b + (size_t)(m16 + 16 * t) * 256 + inrow);
            acc[t] = __builtin_amdgcn_mfma_f32_16x16x32_bf16(A.v, B.v, acc[t], 0, 0, 0);
        }
    }

    // ---- bias + LayerNorm + ReLU (in-register, 16-lane reduce) ----
    float s[4] = {0.f, 0.f, 0.f, 0.f}, sq[4] = {0.f, 0.f, 0.f, 0.f};
#pragma unroll
    for (int t = 0; t < 16; ++t) {
        const float bb = b1s[m16 + 16 * t];
#pragma unroll
        for (int r = 0; r < 4; ++r) {
            acc[t][r] += bb;
            s[r]  += acc[t][r];
            sq[r] += acc[t][r] * acc[t][r];
        }
    }
#pragma unroll
    for (int off = 1; off < 16; off <<= 1)
#pragma unroll
        for (int r = 0; r < 4; ++r) {
            s[r]  += __shfl_xor(s[r],  off);
            sq[r] += __shfl_xor(sq[r], off);
        }
    float mu[4], is[4];
#pragma unroll
    for (int r = 0; r < 4; ++r) {
        mu[r] = s[r] * (1.0f / 256.0f);
        const float var = sq[r] * (1.0f / 256.0f) - mu[r] * mu[r];
        is[r] = rsqrtf(var + LN_EPS);
    }

    __syncthreads();   // all waves done reading w1t -> safe to overwrite

    // ---- write h1 tile (16 rows x 256 cols bf16) into own w1t slice ----
    char* hls = (char*)w1t + w * 8192;
#pragma unroll
    for (int t = 0; t < 16; ++t) {
        const int c = m16 + 16 * t;
        const float g = gs[c], b = bs[c];
#pragma unroll
        for (int r = 0; r < 4; ++r) {
            const int row = q * 4 + r;
            const float o = fmaxf((acc[t][r] - mu[r]) * is[r] * g + b, 0.0f);
            *(ushort*)(hls + row * 512 + ((2 * c) ^ (row << 4))) = f2bf(o);
        }
    }
    __syncthreads();   // order ds_writes before ds_reads (conservative)

    // ---- GEMM2: [16 x 256] @ [256 x 128] ----
    f32x4 acc2[8];
#pragma unroll
    for (int t = 0; t < 8; ++t) acc2[t] = (f32x4){0.f, 0.f, 0.f, 0.f};

    const char* w2b = (const char*)w2t;
#pragma unroll
    for (int ks = 0; ks < 8; ++ks) {
        const int inrow = (ks * 64 + q * 16) ^ (m16 << 4);
        U16 A; A.u = *(const uint4*)(hls + m16 * 512 + inrow);
#pragma unroll
        for (int t = 0; t < 8; ++t) {
            U16 B; B.u = *(const uint4*)(w2b + (size_t)(m16 + 16 * t) * 512 + inrow);
            acc2[t] = __builtin_amdgcn_mfma_f32_16x16x32_bf16(A.v, B.v, acc2[t], 0, 0, 0);
        }
    }
#pragma unroll
    for (int t = 0; t < 8; ++t) {
        const int c = m16 + 16 * t;
        const float bb = b2[c];
#pragma unroll
        for (int r = 0; r < 4; ++r) {
            const int row = n0 + q * 4 + r;
            if (row < NNODES)
                out[(size_t)row * CIN + c] = acc2[t][r] + bb;
        }
    }
}

// ---------------------------------------------------------------------------
extern "C" void kernel_launch(void* const* d_in, const int* in_sizes, int n_in,
                              void* d_out, int out_size, void* d_ws, size_t ws_size,
                              hipStream_t stream)
{
    const float* x     = (const float*)d_in[0];
    const int*   ei    = (const int*)d_in[1];
    const float* ea    = (const float*)d_in[2];
    const float* We    = (const float*)d_in[3];
    const float* be    = (const float*)d_in[4];
    const float* W1    = (const float*)d_in[5];
    const float* b1    = (const float*)d_in[6];
    const float* gamma = (const float*)d_in[7];
    const float* beta  = (const float*)d_in[8];
    const float* W2    = (const float*)d_in[9];
    const float* b2    = (const float*)d_in[10];
    const float* eps   = (const float*)d_in[11];

    // ws layout (512-aligned), total ~195.4 MB (ws is ~655 MB):
    char* wsB = (char*)d_ws;
    uint32_t* hbf = (uint32_t*)wsB;                         // 25,600,000 B
    int* rowptr = (int*)(wsB + 25600000);                   //    400,004 B
    int* cursor = (int*)(wsB + 26000512);                   //    400,000 B
    int* perm   = (int*)(wsB + 26401024);                   //  2,560,000 B
    int* srcS   = (int*)(wsB + 28961024);                   //  2,560,000 B
    int* chunks = (int*)(wsB + 31521024);                   //      4,096 B
    ushort* msgS = (ushort*)(wsB + 31525120);               // 163,840,000 B

    k_zero <<<(NNODES + 255) / 256, 256, 0, stream>>>(cursor);
    k_hist <<<NEDGES / 256, 256, 0, stream>>>(ei, cursor);
    k_scanA<<<4, 256, 0, stream>>>(cursor, chunks);
    k_scanB<<<1, 1024, 0, stream>>>(chunks);
    k_scanC<<<4, 256, 0, stream>>>(cursor, chunks, rowptr);
    k_fill <<<NEDGES / 256, 256, 0, stream>>>(ei, cursor, perm, srcS);

    k_emsg<<<2560, 256, 0, stream>>>(ea, We, perm, msgS);
    k_gsum<<<NNODES / 4, 256, 0, stream>>>(x, srcS, msgS, be, rowptr, eps, hbf);

    k23_fused<<<(NNODES + 127) / 128, 512, 0, stream>>>(hbf, W1, b1, gamma, beta,
                                                        W2, b2, (float*)d_out);
}

// Round 5
// 357.170 us; speedup vs baseline: 2.9263x; 1.1801x over previous
//
#include <hip/hip_runtime.h>
#include <hip/hip_bf16.h>
#include <stdint.h>

#define NNODES 100000
#define NEDGES 640000
#define CIN 128
#define EDIM 64
#define C2 256
#define LN_EPS 1e-5f
#define NW 6144            // gather waves (1536 blocks x 4)
#define PP 105             // ceil(NEDGES / NW)

typedef __attribute__((ext_vector_type(8))) short bf16x8;
typedef __attribute__((ext_vector_type(4))) float f32x4;

__device__ __forceinline__ ushort f2bf(float f) {
    uint32_t u = __float_as_uint(f);
    uint32_t r = (u + 0x7fffu + ((u >> 16) & 1u)) >> 16;   // RNE
    return (ushort)r;
}
__device__ __forceinline__ float bf2f_lo(uint32_t u) { return __uint_as_float(u << 16); }
__device__ __forceinline__ float bf2f_hi(uint32_t u) { return __uint_as_float(u & 0xffff0000u); }

union U16 { uint4 u; bf16x8 v; };

// ---------------------------------------------------------------------------
// k_zero: compute-queue zero of cursor (graph-captured memset = blit-queue
// switch, ~91us — measured r3).
// ---------------------------------------------------------------------------
__global__ __launch_bounds__(256) void k_zero(int* __restrict__ p)
{
    const int i = blockIdx.x * 256 + threadIdx.x;
    if (i < NNODES) p[i] = 0;
}

// ---------------------------------------------------------------------------
// CSR build: histogram -> 2-level exclusive scan -> fill (perm, srcS, dstS).
// ---------------------------------------------------------------------------
__global__ __launch_bounds__(256) void k_hist(const int* __restrict__ ei,
                                              int* __restrict__ counts)
{
    const int e = blockIdx.x * 256 + threadIdx.x;
    atomicAdd(&counts[ei[e]], 1);
}

#define CHUNK 98   // 1024 * 98 >= 100000

__global__ __launch_bounds__(256) void k_scanA(const int* __restrict__ counts,
                                               int* __restrict__ chunks)
{
    const int c = blockIdx.x * 256 + threadIdx.x;
    const int n0 = c * CHUNK;
    const int n1 = min(n0 + CHUNK, NNODES);
    int s = 0;
    for (int n = n0; n < n1; ++n) s += counts[n];
    chunks[c] = s;
}

__global__ __launch_bounds__(1024) void k_scanB(int* __restrict__ chunks)
{
    __shared__ int ws[16];
    const int t = threadIdx.x, lane = t & 63, wv = t >> 6;
    const int v = chunks[t];
    int s = v;
#pragma unroll
    for (int off = 1; off < 64; off <<= 1) {
        const int u = __shfl_up(s, off);
        if (lane >= off) s += u;
    }
    if (lane == 63) ws[wv] = s;
    __syncthreads();
    if (t < 16) {
        const int u = ws[t];
        int ss = u;
#pragma unroll
        for (int off = 1; off < 16; off <<= 1) {
            const int uu = __shfl_up(ss, off);
            if (lane >= off) ss += uu;
        }
        ws[t] = ss - u;
    }
    __syncthreads();
    chunks[t] = s - v + ws[wv];
}

__global__ __launch_bounds__(256) void k_scanC(int* __restrict__ cursor,
                                               const int* __restrict__ chunks,
                                               int* __restrict__ rowptr)
{
    const int c = blockIdx.x * 256 + threadIdx.x;
    const int n0 = c * CHUNK;
    const int n1 = min(n0 + CHUNK, NNODES);
    int run = chunks[c];
    for (int n = n0; n < n1; ++n) {
        const int d = cursor[n];
        rowptr[n] = run;
        cursor[n] = run;
        run += d;
    }
    if (n1 == NNODES && n0 < NNODES) rowptr[NNODES] = run;
}

__global__ __launch_bounds__(256) void k_fill(const int* __restrict__ ei,
                                              int* __restrict__ cursor,
                                              int* __restrict__ perm,
                                              int* __restrict__ srcS,
                                              int* __restrict__ dstS)
{
    const int e = blockIdx.x * 256 + threadIdx.x;
    const int d = ei[e];
    const int pos = atomicAdd(&cursor[d], 1);
    perm[pos] = e;
    srcS[pos] = ei[NEDGES + e];
    dstS[pos] = d;
}

// ---------------------------------------------------------------------------
// k_part: node-aligned equal-work partition. naw[w] = first n with
// rowptr[n] >= w*PP (wave w owns nodes [naw[w], naw[w+1])).
// ---------------------------------------------------------------------------
__global__ __launch_bounds__(256) void k_part(const int* __restrict__ rowptr,
                                              int* __restrict__ naw)
{
    const int w = blockIdx.x * 256 + threadIdx.x;
    if (w > NW) return;
    const int target = min(w * PP, NEDGES);
    int lo = 0, hi = NNODES;
    while (lo < hi) {
        const int mid = (lo + hi) >> 1;
        if (rowptr[mid] < target) lo = mid + 1; else hi = mid;
    }
    naw[w] = lo;
}

// ---------------------------------------------------------------------------
// k_h0: zero hbf rows of degree-0 nodes (~0.17%); k_edge never flushes them.
// ---------------------------------------------------------------------------
__global__ __launch_bounds__(256) void k_h0(const int* __restrict__ rowptr,
                                            uint32_t* __restrict__ hbf)
{
    const int n = blockIdx.x * 256 + threadIdx.x;
    if (n < NNODES && rowptr[n] == rowptr[n + 1]) {
        uint32_t* r = hbf + (size_t)n * 64;
#pragma unroll
        for (int i = 0; i < 64; ++i) r[i] = 0;
    }
}

// ---------------------------------------------------------------------------
// k_edge: FUSED edge-GEMM + gather (msgS round-trip eliminated, -320MB HBM).
// Wave owns positions [rowptr[naw[w]], rowptr[naw[w+1]]). Per 16-pos tile:
//   MFMA (We in 64 VGPR) -> wave-private LDS (f32, XOR-swizzled, <=2-way)
//   x[src] rows prefetched to 16 float2 regs (addresses scalarized via
//   readlane -> global_load with SGPR base), hidden under the MFMA.
//   Unrolled consume: msg ds_read_b64 + x + be, relu, accumulate; flush on
//   node change from sorted dstS (sum-only: (1+eps)x moved into k23).
// ---------------------------------------------------------------------------
__global__ __launch_bounds__(256, 3) void k_edge(
    const float* __restrict__ x, const float* __restrict__ ea,
    const float* __restrict__ We, const float* __restrict__ be,
    const int* __restrict__ perm, const int* __restrict__ srcS,
    const int* __restrict__ dstS, const int* __restrict__ naw,
    const int* __restrict__ rowptr, uint32_t* __restrict__ hbf)
{
    __shared__ float msgl[4 * 16 * 128];          // 32 KB: 8KB per wave
    const int tid = threadIdx.x;
    const int l = tid & 63, q = l >> 4, m16 = l & 15;
    const int wv = tid >> 6;
    const int w = blockIdx.x * 4 + wv;

    // We fragments: B[k][c], lane (q,m16): k = ks*32+q*8+j, c = m16+16t
    bf16x8 bfw[2][8];
#pragma unroll
    for (int ks = 0; ks < 2; ++ks)
#pragma unroll
        for (int t = 0; t < 8; ++t) {
            const int c = m16 + 16 * t;
#pragma unroll
            for (int j = 0; j < 8; ++j)
                bfw[ks][t][j] = (short)f2bf(We[(ks * 32 + q * 8 + j) * CIN + c]);
        }
    const float2 bev = ((const float2*)be)[l];
    const float2* __restrict__ x2 = (const float2*)x;

    const int n0 = naw[w], n1 = naw[w + 1];
    const int ps = rowptr[n0], pe = rowptr[n1];
    char* msb = (char*)msgl + wv * 8192;

    int cur = -1;
    float a0 = 0.f, a1 = 0.f;

    for (int ts = ps; ts < pe; ts += 16) {
        const int nt = min(16, pe - ts);
        const int pp = min(ts + m16, NEDGES - 1);
        const int ep = perm[pp];
        const int sb = srcS[pp];
        const int db = dstS[pp];

        // ---- x-row prefetch (16 independent loads, SGPR-based addresses) ----
        float2 xr[16];
#pragma unroll
        for (int jj = 0; jj < 16; ++jj) {
            const int sj = __builtin_amdgcn_readlane(sb, jj);
            if (jj < nt) xr[jj] = x2[(size_t)sj * 64 + l];
        }

        // ---- A fragments (this lane's ea row, 2 K-steps) ----
        const float* ar = ea + (size_t)ep * EDIM + q * 8;
        const float4 f0 = *(const float4*)ar;
        const float4 f1 = *(const float4*)(ar + 4);
        const float4 g0 = *(const float4*)(ar + 32);
        const float4 g1 = *(const float4*)(ar + 36);
        bf16x8 A0, A1;
        A0[0] = (short)f2bf(f0.x); A0[1] = (short)f2bf(f0.y);
        A0[2] = (short)f2bf(f0.z); A0[3] = (short)f2bf(f0.w);
        A0[4] = (short)f2bf(f1.x); A0[5] = (short)f2bf(f1.y);
        A0[6] = (short)f2bf(f1.z); A0[7] = (short)f2bf(f1.w);
        A1[0] = (short)f2bf(g0.x); A1[1] = (short)f2bf(g0.y);
        A1[2] = (short)f2bf(g0.z); A1[3] = (short)f2bf(g0.w);
        A1[4] = (short)f2bf(g1.x); A1[5] = (short)f2bf(g1.y);
        A1[6] = (short)f2bf(g1.z); A1[7] = (short)f2bf(g1.w);

        // ---- MFMA in two 64-col halves (acc = 16 VGPR) + LDS store ----
#pragma unroll
        for (int hf = 0; hf < 2; ++hf) {
            f32x4 acc[4];
#pragma unroll
            for (int t4 = 0; t4 < 4; ++t4) acc[t4] = (f32x4){0.f, 0.f, 0.f, 0.f};
#pragma unroll
            for (int t4 = 0; t4 < 4; ++t4) {
                acc[t4] = __builtin_amdgcn_mfma_f32_16x16x32_bf16(A0, bfw[0][hf * 4 + t4], acc[t4], 0, 0, 0);
                acc[t4] = __builtin_amdgcn_mfma_f32_16x16x32_bf16(A1, bfw[1][hf * 4 + t4], acc[t4], 0, 0, 0);
            }
#pragma unroll
            for (int t4 = 0; t4 < 4; ++t4) {
                const int col = m16 + 16 * (hf * 4 + t4);
#pragma unroll
                for (int r = 0; r < 4; ++r) {
                    const int row = q * 4 + r;
                    *(float*)(msb + row * 512 + ((4 * col) ^ ((row & 7) << 4))) = acc[t4][r];
                }
            }
        }

        // ---- consume: relu(x + msg + be), accumulate, flush on node change --
#pragma unroll
        for (int jj = 0; jj < 16; ++jj) {
            if (jj < nt) {
                const int dj = __builtin_amdgcn_readlane(db, jj);
                if (dj != cur) {
                    if (cur >= 0)
                        hbf[(size_t)cur * 64 + l] =
                            (uint32_t)f2bf(a0) | ((uint32_t)f2bf(a1) << 16);
                    cur = dj; a0 = 0.f; a1 = 0.f;
                }
                const float2 mv = *(const float2*)(msb + jj * 512 + ((8 * l) ^ ((jj & 7) << 4)));
                a0 += fmaxf(xr[jj].x + mv.x + bev.x, 0.f);
                a1 += fmaxf(xr[jj].y + mv.y + bev.y, 0.f);
            }
        }
    }
    if (cur >= 0)
        hbf[(size_t)cur * 64 + l] = (uint32_t)f2bf(a0) | ((uint32_t)f2bf(a1) << 16);
}

// ---------------------------------------------------------------------------
// Fused MLP: out = relu(LN(h@W1+b1))@W2 + b2 where h = (1+eps)*x + msum
// (msum = hbf, bf16; the (1+eps)x term folded into the A-fragment build).
// h1 tile stays in LDS (overwrites dead w1t). Swizzle byte ^= (c&15)<<4.
// ---------------------------------------------------------------------------
__global__ __launch_bounds__(512, 2) void k23_fused(
    const uint32_t* __restrict__ hbf, const float* __restrict__ x,
    const float* __restrict__ eps, const float* __restrict__ W1,
    const float* __restrict__ b1, const float* __restrict__ gamma,
    const float* __restrict__ beta, const float* __restrict__ W2,
    const float* __restrict__ b2, float* __restrict__ out)
{
    __shared__ ushort w1t[CIN * C2];      // 64 KB (later: h1 tiles, 8KB/wave)
    __shared__ ushort w2t[C2 * CIN];      // 64 KB
    __shared__ float b1s[C2], gs[C2], bs[C2];

    const int tid = threadIdx.x;
    for (int i = tid; i < CIN * C2; i += 512) {     // W1[k][c] -> W1T swizzled
        const int k = i >> 8, c = i & 255;
        *(ushort*)((char*)w1t + (size_t)c * 256 + ((2 * k) ^ ((c & 15) << 4))) = f2bf(W1[i]);
    }
    for (int i = tid; i < C2 * CIN; i += 512) {     // W2[k][c] -> W2T swizzled
        const int k = i >> 7, c = i & 127;
        *(ushort*)((char*)w2t + (size_t)c * 512 + ((2 * k) ^ ((c & 15) << 4))) = f2bf(W2[i]);
    }
    if (tid < C2) { b1s[tid] = b1[tid]; gs[tid] = gamma[tid]; bs[tid] = beta[tid]; }
    const float s1p = 1.0f + eps[0];
    __syncthreads();

    const int l = tid & 63, q = l >> 4, m16 = l & 15;
    const int w = tid >> 6;
    const int n0 = blockIdx.x * 128 + w * 16;
    const int rowA = min(n0 + m16, NNODES - 1);

    // ---- GEMM1: [16 x 128] @ [128 x 256], A = (1+eps)x + msum on the fly ----
    f32x4 acc[16];
#pragma unroll
    for (int t = 0; t < 16; ++t) acc[t] = (f32x4){0.f, 0.f, 0.f, 0.f};

    const char* w1b = (const char*)w1t;
#pragma unroll
    for (int ks = 0; ks < 4; ++ks) {
        const uint4 su = *(const uint4*)(hbf + (size_t)rowA * 64 + ks * 16 + q * 4);
        const float* xp = x + (size_t)rowA * CIN + ks * 32 + q * 8;
        const float4 xa = *(const float4*)xp;
        const float4 xb = *(const float4*)(xp + 4);
        U16 A;
        A.v[0] = (short)f2bf(fmaf(s1p, xa.x, bf2f_lo(su.x)));
        A.v[1] = (short)f2bf(fmaf(s1p, xa.y, bf2f_hi(su.x)));
        A.v[2] = (short)f2bf(fmaf(s1p, xa.z, bf2f_lo(su.y)));
        A.v[3] = (short)f2bf(fmaf(s1p, xa.w, bf2f_hi(su.y)));
        A.v[4] = (short)f2bf(fmaf(s1p, xb.x, bf2f_lo(su.z)));
        A.v[5] = (short)f2bf(fmaf(s1p, xb.y, bf2f_hi(su.z)));
        A.v[6] = (short)f2bf(fmaf(s1p, xb.z, bf2f_lo(su.w)));
        A.v[7] = (short)f2bf(fmaf(s1p, xb.w, bf2f_hi(su.w)));
        const int inrow = (ks * 64 + q * 16) ^ (m16 << 4);
#pragma unroll
        for (int t = 0; t < 16; ++t) {
            U16 B; B.u = *(const uint4*)(w1b + (size_t)(m16 + 16 * t) * 256 + inrow);
            acc[t] = __builtin_amdgcn_mfma_f32_16x16x32_bf16(A.v, B.v, acc[t], 0, 0, 0);
        }
    }

    // ---- bias + LayerNorm + ReLU ----
    float s[4] = {0.f, 0.f, 0.f, 0.f}, sq[4] = {0.f, 0.f, 0.f, 0.f};
#pragma unroll
    for (int t = 0; t < 16; ++t) {
        const float bb = b1s[m16 + 16 * t];
#pragma unroll
        for (int r = 0; r < 4; ++r) {
            acc[t][r] += bb;
            s[r]  += acc[t][r];
            sq[r] += acc[t][r] * acc[t][r];
        }
    }
#pragma unroll
    for (int off = 1; off < 16; off <<= 1)
#pragma unroll
        for (int r = 0; r < 4; ++r) {
            s[r]  += __shfl_xor(s[r],  off);
            sq[r] += __shfl_xor(sq[r], off);
        }
    float mu[4], is[4];
#pragma unroll
    for (int r = 0; r < 4; ++r) {
        mu[r] = s[r] * (1.0f / 256.0f);
        const float var = sq[r] * (1.0f / 256.0f) - mu[r] * mu[r];
        is[r] = rsqrtf(var + LN_EPS);
    }

    __syncthreads();   // all waves done reading w1t -> safe to overwrite

    // ---- h1 tile (16 x 256 bf16) into own w1t slice ----
    char* hls = (char*)w1t + w * 8192;
#pragma unroll
    for (int t = 0; t < 16; ++t) {
        const int c = m16 + 16 * t;
        const float g = gs[c], b = bs[c];
#pragma unroll
        for (int r = 0; r < 4; ++r) {
            const int row = q * 4 + r;
            const float o = fmaxf((acc[t][r] - mu[r]) * is[r] * g + b, 0.0f);
            *(ushort*)(hls + row * 512 + ((2 * c) ^ (row << 4))) = f2bf(o);
        }
    }
    __syncthreads();

    // ---- GEMM2: [16 x 256] @ [256 x 128] ----
    f32x4 acc2[8];
#pragma unroll
    for (int t = 0; t < 8; ++t) acc2[t] = (f32x4){0.f, 0.f, 0.f, 0.f};

    const char* w2b = (const char*)w2t;
#pragma unroll
    for (int ks = 0; ks < 8; ++ks) {
        const int inrow = (ks * 64 + q * 16) ^ (m16 << 4);
        U16 A; A.u = *(const uint4*)(hls + m16 * 512 + inrow);
#pragma unroll
        for (int t = 0; t < 8; ++t) {
            U16 B; B.u = *(const uint4*)(w2b + (size_t)(m16 + 16 * t) * 512 + inrow);
            acc2[t] = __builtin_amdgcn_mfma_f32_16x16x32_bf16(A.v, B.v, acc2[t], 0, 0, 0);
        }
    }
#pragma unroll
    for (int t = 0; t < 8; ++t) {
        const int c = m16 + 16 * t;
        const float bb = b2[c];
#pragma unroll
        for (int r = 0; r < 4; ++r) {
            const int row = n0 + q * 4 + r;
            if (row < NNODES)
                out[(size_t)row * CIN + c] = acc2[t][r] + bb;
        }
    }
}

// ---------------------------------------------------------------------------
extern "C" void kernel_launch(void* const* d_in, const int* in_sizes, int n_in,
                              void* d_out, int out_size, void* d_ws, size_t ws_size,
                              hipStream_t stream)
{
    const float* x     = (const float*)d_in[0];
    const int*   ei    = (const int*)d_in[1];
    const float* ea    = (const float*)d_in[2];
    const float* We    = (const float*)d_in[3];
    const float* be    = (const float*)d_in[4];
    const float* W1    = (const float*)d_in[5];
    const float* b1    = (const float*)d_in[6];
    const float* gamma = (const float*)d_in[7];
    const float* beta  = (const float*)d_in[8];
    const float* W2    = (const float*)d_in[9];
    const float* b2    = (const float*)d_in[10];
    const float* eps   = (const float*)d_in[11];

    // ws layout (512-aligned), ~34.1 MB of ~655 MB:
    char* wsB = (char*)d_ws;
    uint32_t* hbf = (uint32_t*)wsB;                         // 25,600,000 B (msum bf16-packed)
    int* rowptr = (int*)(wsB + 25600000);                   //    400,004 B
    int* cursor = (int*)(wsB + 26000512);                   //    400,000 B
    int* perm   = (int*)(wsB + 26401024);                   //  2,560,000 B
    int* srcS   = (int*)(wsB + 28961024);                   //  2,560,000 B
    int* dstS   = (int*)(wsB + 31521024);                   //  2,560,000 B
    int* chunks = (int*)(wsB + 34081024);                   //      4,096 B
    int* naw    = (int*)(wsB + 34085120);                   //     24,580 B

    k_zero <<<(NNODES + 255) / 256, 256, 0, stream>>>(cursor);
    k_hist <<<NEDGES / 256, 256, 0, stream>>>(ei, cursor);
    k_scanA<<<4, 256, 0, stream>>>(cursor, chunks);
    k_scanB<<<1, 1024, 0, stream>>>(chunks);
    k_scanC<<<4, 256, 0, stream>>>(cursor, chunks, rowptr);
    k_fill <<<NEDGES / 256, 256, 0, stream>>>(ei, cursor, perm, srcS, dstS);
    k_part <<<(NW + 256) / 256, 256, 0, stream>>>(rowptr, naw);
    k_h0   <<<(NNODES + 255) / 256, 256, 0, stream>>>(rowptr, hbf);

    k_edge <<<NW / 4, 256, 0, stream>>>(x, ea, We, be, perm, srcS, dstS,
                                        naw, rowptr, hbf);

    k23_fused<<<(NNODES + 127) / 128, 512, 0, stream>>>(hbf, x, eps, W1, b1,
                                                        gamma, beta, W2, b2,
                                                        (float*)d_out);
}